// Round 1
// 935.095 us; speedup vs baseline: 1.0728x; 1.0728x over previous
//
#include <hip/hip_runtime.h>

// Problem constants
#define Bq   8
#define Nn   512
#define Tt   24
#define NIDc 64
#define HIDc 256
#define HORc 24
#define Dd   12376      // Tt + Nn*Tt + NIDc
#define Mm   4096       // Bq*Nn
#define DdPad 12384     // Dd padded to multiple of 32 (K dim of x / W_in^T)
#define NbPad 12416     // Dd padded to multiple of 128 (N-pad for W_b^T rows)
#define SPLITK 8
#define KCHUNK 1568     // 8*1568 >= 12384, mult of 32

typedef float  f32x4  __attribute__((ext_vector_type(4)));
typedef short  bf16x8 __attribute__((ext_vector_type(8)));

__device__ __forceinline__ ushort f2bf(float f) {
    unsigned u = __float_as_uint(f);
    u += 0x7FFF + ((u >> 16) & 1);          // RNE; inputs finite
    return (ushort)(u >> 16);
}
__device__ __forceinline__ float bf2f(ushort h) {
    return __uint_as_float(((unsigned)h) << 16);
}

// async 16B/lane global->LDS: LDS dest = wave-uniform base + lane*16
#define ASYNC16(g, l) __builtin_amdgcn_global_load_lds(                        \
    (const __attribute__((address_space(1))) unsigned*)(g),                    \
    (__attribute__((address_space(3))) unsigned*)(l), 16, 0, 0)

// ---------------------------------------------------------------------------
// build level + x0 (bf16, row stride DdPad, pad cols zeroed)
// ---------------------------------------------------------------------------
__global__ __launch_bounds__(256) void build_x_kernel(
    const float* __restrict__ hist, const int* __restrict__ nid,
    const float* __restrict__ adj, const float* __restrict__ emb,
    ushort* __restrict__ x, float* __restrict__ level)
{
    int bn = blockIdx.x;
    int b  = bn >> 9;
    __shared__ float sh[Tt];
    __shared__ float slv;
    int tid = threadIdx.x;
    const float* hrow = hist + (size_t)bn * Tt;
    if (tid < Tt) sh[tid] = hrow[tid];
    __syncthreads();
    if (tid == 0) {
        float m = sh[0];
        #pragma unroll
        for (int t = 1; t < Tt; t++) m = fmaxf(m, sh[t]);
        slv = m;
        level[bn] = m;
    }
    __syncthreads();
    float lv  = slv;
    float inv = (lv == 0.0f) ? 0.0f : 1.0f / lv;
    ushort* xr = x + (size_t)bn * DdPad;
    if (tid < Tt) xr[tid] = f2bf(sh[tid] * inv);
    const float* hb   = hist + (size_t)b * Nn * Tt;
    const float* arow = adj  + (size_t)bn * Nn;
    // vectorized: 8 consecutive elements per thread -> one 16B store
    for (int base = tid * 8; base < Nn * Tt; base += 256 * 8) {
        bf16x8 pack;
        #pragma unroll
        for (int e = 0; e < 8; e++) {
            int idx = base + e;
            int m_ = idx / Tt;
            int t  = idx - m_ * Tt;
            float v = arow[m_] * hb[m_ * Tt + t];
            float r = (v - lv) * inv;
            pack[e] = (short)f2bf((r > 0.0f) ? r : 0.0f);
        }
        *(bf16x8*)(xr + Tt + base) = pack;   // (Tt+base)*2 = 48+16k: aligned
    }
    if (tid < NIDc) {
        int id = nid[bn];
        xr[Tt + Nn * Tt + tid] = f2bf(emb[(size_t)id * NIDc + tid]);
    }
    if (tid < DdPad - Dd) xr[Dd + tid] = 0;   // zero K-pad cols
}

// ---------------------------------------------------------------------------
// W[K][N] fp32  ->  Bt[n][k] bf16 with K zero-padded to Kpad.
// ---------------------------------------------------------------------------
__global__ __launch_bounds__(256) void transpose_w(
    const float* __restrict__ W, ushort* __restrict__ Bt,
    int K, int N, int Kpad)
{
    __shared__ ushort tile[32][72];
    const int k0 = blockIdx.x * 32;
    const int n0 = blockIdx.y * 64;
    const int tid = threadIdx.x;
    #pragma unroll
    for (int i = 0; i < 8; i++) {
        const int idx = tid + i * 256;
        const int kk = idx >> 6;
        const int nn = idx & 63;
        const int gk = k0 + kk, gn = n0 + nn;
        const float v = (gk < K && gn < N) ? W[(size_t)gk * N + gn] : 0.0f;
        tile[kk][nn] = f2bf(v);
    }
    __syncthreads();
    const int n  = tid >> 2;
    const int kc = (tid & 3) << 3;
    uint4 o;
    o.x = (unsigned)tile[kc + 0][n] | ((unsigned)tile[kc + 1][n] << 16);
    o.y = (unsigned)tile[kc + 2][n] | ((unsigned)tile[kc + 3][n] << 16);
    o.z = (unsigned)tile[kc + 4][n] | ((unsigned)tile[kc + 5][n] << 16);
    o.w = (unsigned)tile[kc + 6][n] | ((unsigned)tile[kc + 7][n] << 16);
    *(uint4*)(Bt + (size_t)(n0 + n) * Kpad + k0 + kc) = o;
}

// ---------------------------------------------------------------------------
// bf16 MFMA GEMM, TMxTN tile, 4 waves (2x2), mfma_f32_16x16x32_bf16.
// A: bf16 row-major [M][lda]; Bt: bf16 [n][k] pre-padded. Staging via
// global_load_lds 16B/lane.
//
// OPERANDS SWAPPED: acc[i][j] = mfma(b_frag, a_frag) computes the transposed
// fragment, so each lane holds 4 CONSECUTIVE output columns:
//   row (M) = row0 + wm + i*16 + l15
//   col (N) = col0 + wn + j*16 + quad*4 + r,  r = 0..3
// -> float4 / ushort4 vector epilogue stores, ushort4 X loads, float4 bias.
//
// EPI 0: fp32 split-K partial (slice = blockIdx.z)
// EPI 1: bf16 h = relu(acc + bias)
// EPI 2: fp32 C = relu(X - (acc + bias)), X bf16 (final backcast), NT stores
// EPI 3: bf16 C = relu(X - (acc + bias)), in-place (X == C)
// ---------------------------------------------------------------------------
template <int TM, int TN, int EPI>
__global__ __launch_bounds__(256) void gemm_mfma(
    const ushort* __restrict__ A, int lda,
    const ushort* __restrict__ Bt, int ldbt,
    const float* __restrict__ bias,
    const ushort* __restrict__ X, int ldx,
    void* __restrict__ Cp, int ldc,
    int K, int N, int chunk)
{
    constexpr int WI = TM / 32;
    constexpr int WJ = TN / 32;
    __shared__ ushort As[TM * 32];
    __shared__ ushort Bs[TN * 32];

    const int tid  = threadIdx.x;
    const int row0 = blockIdx.x * TM;
    const int col0 = blockIdx.y * TN;
    const int spl  = blockIdx.z;
    const int kstart = spl * chunk;
    const int kend   = min(K, kstart + chunk);
    const int iters  = (kend - kstart) >> 5;   // K, chunk multiples of 32

    const int lane = tid & 63;
    const int wave = tid >> 6;
    const int quad = lane >> 4;
    const int l15  = lane & 15;
    const int wm   = (wave >> 1) * (TM / 2);
    const int wn   = (wave & 1) * (TN / 2);

    f32x4 acc[WI][WJ];
    #pragma unroll
    for (int i = 0; i < WI; i++)
        #pragma unroll
        for (int j = 0; j < WJ; j++)
            acc[i][j] = (f32x4){0.f, 0.f, 0.f, 0.f};

    for (int kt = 0; kt < iters; ++kt) {
        const int kb = kstart + (kt << 5);
        #pragma unroll
        for (int s = wave; s < TM / 16; s += 4) {    // 16 bf16 rows / segment
            const int r = s * 16 + (lane >> 2);
            ASYNC16(A + (size_t)(row0 + r) * lda + kb + ((lane & 3) << 3),
                    As + s * 512);
        }
        #pragma unroll
        for (int s = wave; s < TN / 16; s += 4) {
            const int r = s * 16 + (lane >> 2);
            ASYNC16(Bt + (size_t)(col0 + r) * ldbt + kb + ((lane & 3) << 3),
                    Bs + s * 512);
        }
        __syncthreads();

        bf16x8 af[WI], bfr[WJ];
        #pragma unroll
        for (int i = 0; i < WI; i++)
            af[i] = *(const bf16x8*)&As[(wm + i * 16 + l15) * 32 + quad * 8];
        #pragma unroll
        for (int j = 0; j < WJ; j++)
            bfr[j] = *(const bf16x8*)&Bs[(wn + j * 16 + l15) * 32 + quad * 8];
        #pragma unroll
        for (int i = 0; i < WI; i++)
            #pragma unroll
            for (int j = 0; j < WJ; j++)
                acc[i][j] = __builtin_amdgcn_mfma_f32_16x16x32_bf16(
                    bfr[j], af[i], acc[i][j], 0, 0, 0);   // SWAPPED operands
        __syncthreads();
    }

    // Vector epilogue: lane owns 4 consecutive cols at one row.
    #pragma unroll
    for (int i = 0; i < WI; i++) {
        const int row = row0 + wm + i * 16 + l15;
        #pragma unroll
        for (int j = 0; j < WJ; j++) {
            const int c0 = col0 + wn + j * 16 + quad * 4;
            const f32x4 v = acc[i][j];
            if (EPI == 0) {
                *(f32x4*)&((float*)Cp)[(size_t)spl * Mm * HIDc +
                                       (size_t)row * ldc + c0] = v;
            } else if (EPI == 1) {
                const float4 bb = *(const float4*)&bias[c0];
                ushort4 o;
                o.x = f2bf(fmaxf(v[0] + bb.x, 0.f));
                o.y = f2bf(fmaxf(v[1] + bb.y, 0.f));
                o.z = f2bf(fmaxf(v[2] + bb.z, 0.f));
                o.w = f2bf(fmaxf(v[3] + bb.w, 0.f));
                *(ushort4*)&((ushort*)Cp)[(size_t)row * ldc + c0] = o;
            } else if (EPI == 2) {
                if (c0 < N) {        // N%4==0, c0%4==0 -> whole vector valid
                    const float4 bb = *(const float4*)&bias[c0];
                    const ushort4 xq = *(const ushort4*)&X[(size_t)row * ldx + c0];
                    f32x4 o;
                    o[0] = fmaxf(bf2f(xq.x) - (v[0] + bb.x), 0.f);
                    o[1] = fmaxf(bf2f(xq.y) - (v[1] + bb.y), 0.f);
                    o[2] = fmaxf(bf2f(xq.z) - (v[2] + bb.z), 0.f);
                    o[3] = fmaxf(bf2f(xq.w) - (v[3] + bb.w), 0.f);
                    __builtin_nontemporal_store(
                        o, (f32x4*)&((float*)Cp)[(size_t)row * ldc + c0]);
                }
            } else {
                if (c0 < N) {
                    const float4 bb = *(const float4*)&bias[c0];
                    const ushort4 xq = *(const ushort4*)&X[(size_t)row * ldx + c0];
                    ushort4 o;
                    o.x = f2bf(fmaxf(bf2f(xq.x) - (v[0] + bb.x), 0.f));
                    o.y = f2bf(fmaxf(bf2f(xq.y) - (v[1] + bb.y), 0.f));
                    o.z = f2bf(fmaxf(bf2f(xq.z) - (v[2] + bb.z), 0.f));
                    o.w = f2bf(fmaxf(bf2f(xq.w) - (v[3] + bb.w), 0.f));
                    *(ushort4*)&((ushort*)Cp)[(size_t)row * ldc + c0] = o;
                }
            }
        }
    }
}

// ---------------------------------------------------------------------------
// h = relu(sum_s partial[s] + bias) -> bf16   (float4 per thread)
// ---------------------------------------------------------------------------
__global__ __launch_bounds__(256) void reduce_hin(
    const float* __restrict__ partial, const float* __restrict__ bias,
    ushort* __restrict__ h)
{
    const int gid = (blockIdx.x * 256 + threadIdx.x) * 4;
    f32x4 s = *(const f32x4*)&bias[gid & (HIDc - 1)];
    #pragma unroll
    for (int j = 0; j < SPLITK; j++)
        s += *(const f32x4*)&partial[(size_t)j * (Mm * HIDc) + gid];
    ushort4 o;
    o.x = f2bf(fmaxf(s[0], 0.f));
    o.y = f2bf(fmaxf(s[1], 0.f));
    o.z = f2bf(fmaxf(s[2], 0.f));
    o.w = f2bf(fmaxf(s[3], 0.f));
    *(ushort4*)&h[gid] = o;
}

// ---------------------------------------------------------------------------
// fc[4096x24] (+)= h @ Wf + bf   (h bf16, Wf fp32)
// ---------------------------------------------------------------------------
__global__ __launch_bounds__(256) void gemm_forecast_kernel(
    const ushort* __restrict__ h, const float* __restrict__ Wf,
    const float* __restrict__ bf, float* __restrict__ fc, int accumulate)
{
    int gid = blockIdx.x * 256 + threadIdx.x;
    if (gid >= Mm * HORc) return;
    int row = gid / HORc;
    int col = gid - row * HORc;
    const ushort* hr = h + (size_t)row * HIDc;
    float acc = 0.0f;
    #pragma unroll 4
    for (int k = 0; k < HIDc; k++)
        acc = fmaf(bf2f(hr[k]), Wf[k * HORc + col], acc);
    acc += bf[col];
    if (accumulate) fc[gid] += acc;
    else            fc[gid]  = acc;
}

__global__ __launch_bounds__(256) void finalize_kernel(
    const float* __restrict__ fc, const float* __restrict__ level,
    float* __restrict__ out)
{
    int gid = blockIdx.x * 256 + threadIdx.x;
    if (gid >= Mm * HORc) return;
    out[gid] = fc[gid] * level[gid / HORc];
}

// ---------------------------------------------------------------------------
extern "C" void kernel_launch(void* const* d_in, const int* in_sizes, int n_in,
                              void* d_out, int out_size, void* d_ws, size_t ws_size,
                              hipStream_t stream)
{
    const float* hist  = (const float*)d_in[0];
    const int*   nid   = (const int*)  d_in[1];
    const float* adj   = (const float*)d_in[3];
    const float* emb   = (const float*)d_in[4];
    const float* W_in  = (const float*)d_in[5];
    const float* b_in  = (const float*)d_in[6];
    const float* W_hid = (const float*)d_in[7];
    const float* b_hid = (const float*)d_in[8];
    const float* W_f   = (const float*)d_in[9];
    const float* b_f   = (const float*)d_in[10];
    const float* W_b   = (const float*)d_in[11];
    const float* b_b   = (const float*)d_in[12];

    float* bout = (float*)d_out;                       // backcast (B,N,D) fp32
    float* fout = (float*)d_out + (size_t)Mm * Dd;     // forecast region

    // ws layout (~178 MB)
    char* ws = (char*)d_ws;
    size_t off = 0;
    float*  level = (float*) (ws + off); off += 16384;
    float*  fc    = (float*) (ws + off); off += (size_t)Mm * HORc * 4;
    ushort* hA    = (ushort*)(ws + off); off += (size_t)Mm * HIDc * 2;
    ushort* hB    = (ushort*)(ws + off); off += (size_t)Mm * HIDc * 2;
    ushort* WtIn  = (ushort*)(ws + off); off += (size_t)3 * HIDc * DdPad * 2;
    ushort* WtHid = (ushort*)(ws + off); off += (size_t)6 * HIDc * HIDc * 2;
    ushort* WtB   = (ushort*)(ws + off); off += (size_t)3 * NbPad * HIDc * 2;
    float*  part  = (float*) (ws + off); off += (size_t)SPLITK * Mm * HIDc * 4;
    ushort* xb    = (ushort*)(ws + off); off += (size_t)Mm * DdPad * 2;

    build_x_kernel<<<Mm, 256, 0, stream>>>(hist, nid, adj, emb, xb, level);

    for (int i = 0; i < 3; i++)
        transpose_w<<<dim3(DdPad / 32, HIDc / 64), 256, 0, stream>>>(
            W_in + (size_t)i * Dd * HIDc, WtIn + (size_t)i * HIDc * DdPad,
            Dd, HIDc, DdPad);
    for (int l = 0; l < 6; l++)
        transpose_w<<<dim3(HIDc / 32, HIDc / 64), 256, 0, stream>>>(
            W_hid + (size_t)l * HIDc * HIDc, WtHid + (size_t)l * HIDc * HIDc,
            HIDc, HIDc, HIDc);
    for (int i = 0; i < 3; i++)
        transpose_w<<<dim3(HIDc / 32, NbPad / 64), 256, 0, stream>>>(
            W_b + (size_t)i * HIDc * Dd, WtB + (size_t)i * NbPad * HIDc,
            HIDc, Dd, HIDc);

    for (int i = 0; i < 3; i++) {
        const float* bi  = b_in  + (size_t)i * HIDc;
        const float* bh0 = b_hid + (size_t)(i * 2 + 0) * HIDc;
        const float* bh1 = b_hid + (size_t)(i * 2 + 1) * HIDc;
        const float* Wfi = W_f   + (size_t)i * HIDc * HORc;
        const float* bfi = b_f   + (size_t)i * HORc;
        const float* bbi = b_b   + (size_t)i * Dd;

        // partial[s] = x @ W_in (split-K over K=DdPad), reduce -> hA (bf16)
        gemm_mfma<128, 128, 0>
            <<<dim3(Mm / 128, HIDc / 128, SPLITK), 256, 0, stream>>>(
            xb, DdPad, WtIn + (size_t)i * HIDc * DdPad, DdPad,
            nullptr, nullptr, 0, part, HIDc, DdPad, HIDc, KCHUNK);
        reduce_hin<<<Mm * HIDc / 1024, 256, 0, stream>>>(part, bi, hA);

        // hidden layers (64x64 tiles -> 256 blocks)
        gemm_mfma<64, 64, 1>
            <<<dim3(Mm / 64, HIDc / 64, 1), 256, 0, stream>>>(
            hA, HIDc, WtHid + (size_t)(2 * i) * HIDc * HIDc, HIDc,
            bh0, nullptr, 0, hB, HIDc, HIDc, HIDc, HIDc);
        gemm_mfma<64, 64, 1>
            <<<dim3(Mm / 64, HIDc / 64, 1), 256, 0, stream>>>(
            hB, HIDc, WtHid + (size_t)(2 * i + 1) * HIDc * HIDc, HIDc,
            bh1, nullptr, 0, hA, HIDc, HIDc, HIDc, HIDc);

        // forecast accumulate
        gemm_forecast_kernel<<<(Mm * HORc + 255) / 256, 256, 0, stream>>>(
            hA, Wfi, bfi, fc, i > 0 ? 1 : 0);

        // backcast
        if (i < 2) {
            // xb = relu(xb - (hA @ W_b + b_b)), in-place bf16
            gemm_mfma<128, 128, 3>
                <<<dim3(Mm / 128, NbPad / 128, 1), 256, 0, stream>>>(
                hA, HIDc, WtB + (size_t)i * NbPad * HIDc, HIDc,
                bbi, xb, DdPad, xb, DdPad, HIDc, Dd, HIDc);
        } else {
            // final: bout = relu(xb - (hA @ W_b + b_b)), fp32 output
            gemm_mfma<128, 128, 2>
                <<<dim3(Mm / 128, NbPad / 128, 1), 256, 0, stream>>>(
                hA, HIDc, WtB + (size_t)i * NbPad * HIDc, HIDc,
                bbi, xb, DdPad, bout, Dd, HIDc, Dd, HIDc);
        }
    }

    finalize_kernel<<<(Mm * HORc + 255) / 256, 256, 0, stream>>>(fc, level, fout);
}

// Round 3
// 891.614 us; speedup vs baseline: 1.1251x; 1.0488x over previous
//
#include <hip/hip_runtime.h>

// Problem constants
#define Bq   8
#define Nn   512
#define Tt   24
#define NIDc 64
#define HIDc 256
#define HORc 24
#define Dd   12376      // Tt + Nn*Tt + NIDc
#define Mm   4096       // Bq*Nn
#define DdPad 12384     // Dd padded to multiple of 32 (K dim of x / W_in^T)
#define NbPad 12416     // Dd padded to multiple of 128 (N-pad for W_b^T rows)
#define SPLITK 8
#define KCHUNK 1568     // 8*1568 >= 12384, mult of 32

typedef float  f32x4  __attribute__((ext_vector_type(4)));
typedef short  bf16x8 __attribute__((ext_vector_type(8)));

__device__ __forceinline__ ushort f2bf(float f) {
    unsigned u = __float_as_uint(f);
    u += 0x7FFF + ((u >> 16) & 1);          // RNE; inputs finite
    return (ushort)(u >> 16);
}
__device__ __forceinline__ float bf2f(ushort h) {
    return __uint_as_float(((unsigned)h) << 16);
}

// async 16B/lane global->LDS: LDS dest = wave-uniform base + lane*16
#define ASYNC16(g, l) __builtin_amdgcn_global_load_lds(                        \
    (const __attribute__((address_space(1))) unsigned*)(g),                    \
    (__attribute__((address_space(3))) unsigned*)(l), 16, 0, 0)

// ---------------------------------------------------------------------------
// build level + x0 (bf16, row stride DdPad, pad cols zeroed)
// ---------------------------------------------------------------------------
__global__ __launch_bounds__(256) void build_x_kernel(
    const float* __restrict__ hist, const int* __restrict__ nid,
    const float* __restrict__ adj, const float* __restrict__ emb,
    ushort* __restrict__ x, float* __restrict__ level)
{
    int bn = blockIdx.x;
    int b  = bn >> 9;
    __shared__ float sh[Tt];
    __shared__ float slv;
    int tid = threadIdx.x;
    const float* hrow = hist + (size_t)bn * Tt;
    if (tid < Tt) sh[tid] = hrow[tid];
    __syncthreads();
    if (tid == 0) {
        float m = sh[0];
        #pragma unroll
        for (int t = 1; t < Tt; t++) m = fmaxf(m, sh[t]);
        slv = m;
        level[bn] = m;
    }
    __syncthreads();
    float lv  = slv;
    float inv = (lv == 0.0f) ? 0.0f : 1.0f / lv;
    ushort* xr = x + (size_t)bn * DdPad;
    if (tid < Tt) xr[tid] = f2bf(sh[tid] * inv);
    const float* hb   = hist + (size_t)b * Nn * Tt;
    const float* arow = adj  + (size_t)bn * Nn;
    // vectorized: 8 consecutive elements per thread -> one 16B store
    for (int base = tid * 8; base < Nn * Tt; base += 256 * 8) {
        bf16x8 pack;
        #pragma unroll
        for (int e = 0; e < 8; e++) {
            int idx = base + e;
            int m_ = idx / Tt;
            int t  = idx - m_ * Tt;
            float v = arow[m_] * hb[m_ * Tt + t];
            float r = (v - lv) * inv;
            pack[e] = (short)f2bf((r > 0.0f) ? r : 0.0f);
        }
        *(bf16x8*)(xr + Tt + base) = pack;   // (Tt+base)*2 = 48+16k: aligned
    }
    if (tid < NIDc) {
        int id = nid[bn];
        xr[Tt + Nn * Tt + tid] = f2bf(emb[(size_t)id * NIDc + tid]);
    }
    if (tid < DdPad - Dd) xr[Dd + tid] = 0;   // zero K-pad cols
}

// ---------------------------------------------------------------------------
// W[K][N] fp32  ->  Bt[n][k] bf16 with K zero-padded to Kpad.
// ---------------------------------------------------------------------------
__global__ __launch_bounds__(256) void transpose_w(
    const float* __restrict__ W, ushort* __restrict__ Bt,
    int K, int N, int Kpad)
{
    __shared__ ushort tile[32][72];
    const int k0 = blockIdx.x * 32;
    const int n0 = blockIdx.y * 64;
    const int tid = threadIdx.x;
    #pragma unroll
    for (int i = 0; i < 8; i++) {
        const int idx = tid + i * 256;
        const int kk = idx >> 6;
        const int nn = idx & 63;
        const int gk = k0 + kk, gn = n0 + nn;
        const float v = (gk < K && gn < N) ? W[(size_t)gk * N + gn] : 0.0f;
        tile[kk][nn] = f2bf(v);
    }
    __syncthreads();
    const int n  = tid >> 2;
    const int kc = (tid & 3) << 3;
    uint4 o;
    o.x = (unsigned)tile[kc + 0][n] | ((unsigned)tile[kc + 1][n] << 16);
    o.y = (unsigned)tile[kc + 2][n] | ((unsigned)tile[kc + 3][n] << 16);
    o.z = (unsigned)tile[kc + 4][n] | ((unsigned)tile[kc + 5][n] << 16);
    o.w = (unsigned)tile[kc + 6][n] | ((unsigned)tile[kc + 7][n] << 16);
    *(uint4*)(Bt + (size_t)(n0 + n) * Kpad + k0 + kc) = o;
}

// ---------------------------------------------------------------------------
// bf16 MFMA GEMM, TMxTN tile, 4 waves (2x2), mfma_f32_16x16x32_bf16.
// A: bf16 row-major [M][lda]; Bt: bf16 [n][k] pre-padded.
//
// Pipeline: double-buffered LDS; stage(next) issued BEFORE compute(cur);
// raw s_barrier + counted "s_waitcnt vmcnt(LPW)" so next-tile loads stay in
// flight across the barrier (T3/T4). X/bias prefetched to regs before loop.
//
// OPERANDS SWAPPED: acc = mfma(b_frag, a_frag) -> lane owns 4 consecutive
// cols: row = row0+wm+i*16+l15, col = col0+wn+j*16+quad*4+r.
//
// EPI 0: fp32 split-K partial (slice = blockIdx.z)
// EPI 1: bf16 h = relu(acc + bias)
// EPI 2: fp32 C = relu(X - (acc + bias)), X bf16 (final backcast)
// EPI 3: bf16 C = relu(X - (acc + bias)), in-place (X == C)
// ---------------------------------------------------------------------------
template <int TM, int TN, int EPI>
__global__ __launch_bounds__(256) void gemm_mfma(
    const ushort* __restrict__ A, int lda,
    const ushort* __restrict__ Bt, int ldbt,
    const float* __restrict__ bias,
    const ushort* __restrict__ X, int ldx,
    void* __restrict__ Cp, int ldc,
    int K, int N, int chunk)
{
    constexpr int WI = TM / 32;
    constexpr int WJ = TN / 32;
    constexpr int SA = TM / 16;          // 16-row async segments of A
    constexpr int SB = TN / 16;
    constexpr int LPW = (SA + SB) / 4;   // async loads per wave per stage
    static_assert((SA + SB) % 4 == 0, "uniform loads per wave required");
    static_assert(LPW == 1 || LPW == 2 || LPW == 4, "vmcnt literal");
    __shared__ ushort As[2][TM * 32];
    __shared__ ushort Bs[2][TN * 32];

    const int tid  = threadIdx.x;
    const int row0 = blockIdx.x * TM;
    const int col0 = blockIdx.y * TN;
    const int spl  = blockIdx.z;
    const int kstart = spl * chunk;
    const int kend   = min(K, kstart + chunk);
    const int iters  = (kend - kstart) >> 5;   // K, chunk multiples of 32

    const int lane = tid & 63;
    const int wave = tid >> 6;
    const int quad = lane >> 4;
    const int l15  = lane & 15;
    const int wm   = (wave >> 1) * (TM / 2);
    const int wn   = (wave & 1) * (TN / 2);

    f32x4 acc[WI][WJ];
    #pragma unroll
    for (int i = 0; i < WI; i++)
        #pragma unroll
        for (int j = 0; j < WJ; j++)
            acc[i][j] = (f32x4){0.f, 0.f, 0.f, 0.f};

    auto stage = [&](int buf, int kb) {
        #pragma unroll
        for (int t = 0; t < LPW; t++) {
            const int s = wave + 4 * t;
            if (s < SA) {
                const int r = s * 16 + (lane >> 2);
                ASYNC16(A + (size_t)(row0 + r) * lda + kb + ((lane & 3) << 3),
                        &As[buf][s * 512]);
            } else {
                const int s2 = s - SA;
                const int r = s2 * 16 + (lane >> 2);
                ASYNC16(Bt + (size_t)(col0 + r) * ldbt + kb + ((lane & 3) << 3),
                        &Bs[buf][s2 * 512]);
            }
        }
    };

    stage(0, kstart);

    // epilogue operand prefetch (latency hides under the whole K-loop)
    float4  bpre[WJ];
    ushort4 xpre[WI][WJ];
    bool    cok[WJ];
    #pragma unroll
    for (int j = 0; j < WJ; j++) {
        const int c0 = col0 + wn + j * 16 + quad * 4;
        cok[j] = (c0 < N);     // Dd%4==0 -> whole 4-vector valid iff c0<N
        if constexpr (EPI == 1) {
            bpre[j] = *(const float4*)&bias[c0];
        } else if constexpr (EPI >= 2) {
            bpre[j] = cok[j] ? *(const float4*)&bias[c0]
                             : float4{0.f, 0.f, 0.f, 0.f};
        }
    }
    if constexpr (EPI >= 2) {
        #pragma unroll
        for (int i = 0; i < WI; i++) {
            const int row = row0 + wm + i * 16 + l15;
            #pragma unroll
            for (int j = 0; j < WJ; j++) {
                const int c0 = col0 + wn + j * 16 + quad * 4;
                xpre[i][j] = cok[j]
                    ? *(const ushort4*)&X[(size_t)row * ldx + c0]
                    : ushort4{0, 0, 0, 0};
            }
        }
    }

    for (int kt = 0; kt < iters; ++kt) {
        const int cur = kt & 1;
        if (kt + 1 < iters) {
            stage(cur ^ 1, kstart + ((kt + 1) << 5));
            // wait for everything except the LPW loads just issued
            if constexpr (LPW == 4)
                asm volatile("s_waitcnt vmcnt(4)" ::: "memory");
            else if constexpr (LPW == 2)
                asm volatile("s_waitcnt vmcnt(2)" ::: "memory");
            else
                asm volatile("s_waitcnt vmcnt(1)" ::: "memory");
        } else {
            asm volatile("s_waitcnt vmcnt(0)" ::: "memory");
        }
        __builtin_amdgcn_s_barrier();          // cur fully staged, all waves
        __builtin_amdgcn_sched_barrier(0);     // pin: no hoist above barrier

        bf16x8 af[WI], bfr[WJ];
        #pragma unroll
        for (int i = 0; i < WI; i++)
            af[i] = *(const bf16x8*)&As[cur][(wm + i * 16 + l15) * 32 + quad * 8];
        #pragma unroll
        for (int j = 0; j < WJ; j++)
            bfr[j] = *(const bf16x8*)&Bs[cur][(wn + j * 16 + l15) * 32 + quad * 8];
        #pragma unroll
        for (int i = 0; i < WI; i++)
            #pragma unroll
            for (int j = 0; j < WJ; j++)
                acc[i][j] = __builtin_amdgcn_mfma_f32_16x16x32_bf16(
                    bfr[j], af[i], acc[i][j], 0, 0, 0);   // SWAPPED operands

        __builtin_amdgcn_sched_barrier(0);     // pin: no sink below barrier
        __builtin_amdgcn_s_barrier();          // cur free for restaging
    }

    // Vector epilogue: lane owns 4 consecutive cols at one row.
    #pragma unroll
    for (int i = 0; i < WI; i++) {
        const int row = row0 + wm + i * 16 + l15;
        #pragma unroll
        for (int j = 0; j < WJ; j++) {
            const int c0 = col0 + wn + j * 16 + quad * 4;
            const f32x4 v = acc[i][j];
            if constexpr (EPI == 0) {
                *(f32x4*)&((float*)Cp)[(size_t)spl * Mm * HIDc +
                                       (size_t)row * ldc + c0] = v;
            } else if constexpr (EPI == 1) {
                ushort4 o;
                o.x = f2bf(fmaxf(v[0] + bpre[j].x, 0.f));
                o.y = f2bf(fmaxf(v[1] + bpre[j].y, 0.f));
                o.z = f2bf(fmaxf(v[2] + bpre[j].z, 0.f));
                o.w = f2bf(fmaxf(v[3] + bpre[j].w, 0.f));
                *(ushort4*)&((ushort*)Cp)[(size_t)row * ldc + c0] = o;
            } else if constexpr (EPI == 2) {
                if (cok[j]) {
                    f32x4 o;
                    o[0] = fmaxf(bf2f(xpre[i][j].x) - (v[0] + bpre[j].x), 0.f);
                    o[1] = fmaxf(bf2f(xpre[i][j].y) - (v[1] + bpre[j].y), 0.f);
                    o[2] = fmaxf(bf2f(xpre[i][j].z) - (v[2] + bpre[j].z), 0.f);
                    o[3] = fmaxf(bf2f(xpre[i][j].w) - (v[3] + bpre[j].w), 0.f);
                    *(f32x4*)&((float*)Cp)[(size_t)row * ldc + c0] = o;
                }
            } else {
                if (cok[j]) {
                    ushort4 o;
                    o.x = f2bf(fmaxf(bf2f(xpre[i][j].x) - (v[0] + bpre[j].x), 0.f));
                    o.y = f2bf(fmaxf(bf2f(xpre[i][j].y) - (v[1] + bpre[j].y), 0.f));
                    o.z = f2bf(fmaxf(bf2f(xpre[i][j].z) - (v[2] + bpre[j].z), 0.f));
                    o.w = f2bf(fmaxf(bf2f(xpre[i][j].w) - (v[3] + bpre[j].w), 0.f));
                    *(ushort4*)&((ushort*)Cp)[(size_t)row * ldc + c0] = o;
                }
            }
        }
    }
}

// ---------------------------------------------------------------------------
// h = relu(sum_s partial[s] + bias) -> bf16   (float4 per thread)
// ---------------------------------------------------------------------------
__global__ __launch_bounds__(256) void reduce_hin(
    const float* __restrict__ partial, const float* __restrict__ bias,
    ushort* __restrict__ h)
{
    const int gid = (blockIdx.x * 256 + threadIdx.x) * 4;
    f32x4 s = *(const f32x4*)&bias[gid & (HIDc - 1)];
    #pragma unroll
    for (int j = 0; j < SPLITK; j++)
        s += *(const f32x4*)&partial[(size_t)j * (Mm * HIDc) + gid];
    ushort4 o;
    o.x = f2bf(fmaxf(s[0], 0.f));
    o.y = f2bf(fmaxf(s[1], 0.f));
    o.z = f2bf(fmaxf(s[2], 0.f));
    o.w = f2bf(fmaxf(s[3], 0.f));
    *(ushort4*)&h[gid] = o;
}

// ---------------------------------------------------------------------------
// fc[4096x24] (+)= h @ Wf + bf   (h bf16, Wf fp32)
// ---------------------------------------------------------------------------
__global__ __launch_bounds__(256) void gemm_forecast_kernel(
    const ushort* __restrict__ h, const float* __restrict__ Wf,
    const float* __restrict__ bf, float* __restrict__ fc, int accumulate)
{
    int gid = blockIdx.x * 256 + threadIdx.x;
    if (gid >= Mm * HORc) return;
    int row = gid / HORc;
    int col = gid - row * HORc;
    const ushort* hr = h + (size_t)row * HIDc;
    float acc = 0.0f;
    #pragma unroll 4
    for (int k = 0; k < HIDc; k++)
        acc = fmaf(bf2f(hr[k]), Wf[k * HORc + col], acc);
    acc += bf[col];
    if (accumulate) fc[gid] += acc;
    else            fc[gid]  = acc;
}

__global__ __launch_bounds__(256) void finalize_kernel(
    const float* __restrict__ fc, const float* __restrict__ level,
    float* __restrict__ out)
{
    int gid = blockIdx.x * 256 + threadIdx.x;
    if (gid >= Mm * HORc) return;
    out[gid] = fc[gid] * level[gid / HORc];
}

// ---------------------------------------------------------------------------
extern "C" void kernel_launch(void* const* d_in, const int* in_sizes, int n_in,
                              void* d_out, int out_size, void* d_ws, size_t ws_size,
                              hipStream_t stream)
{
    const float* hist  = (const float*)d_in[0];
    const int*   nid   = (const int*)  d_in[1];
    const float* adj   = (const float*)d_in[3];
    const float* emb   = (const float*)d_in[4];
    const float* W_in  = (const float*)d_in[5];
    const float* b_in  = (const float*)d_in[6];
    const float* W_hid = (const float*)d_in[7];
    const float* b_hid = (const float*)d_in[8];
    const float* W_f   = (const float*)d_in[9];
    const float* b_f   = (const float*)d_in[10];
    const float* W_b   = (const float*)d_in[11];
    const float* b_b   = (const float*)d_in[12];

    float* bout = (float*)d_out;                       // backcast (B,N,D) fp32
    float* fout = (float*)d_out + (size_t)Mm * Dd;     // forecast region

    // ws layout (~178 MB)
    char* ws = (char*)d_ws;
    size_t off = 0;
    float*  level = (float*) (ws + off); off += 16384;
    float*  fc    = (float*) (ws + off); off += (size_t)Mm * HORc * 4;
    ushort* hA    = (ushort*)(ws + off); off += (size_t)Mm * HIDc * 2;
    ushort* hB    = (ushort*)(ws + off); off += (size_t)Mm * HIDc * 2;
    ushort* WtIn  = (ushort*)(ws + off); off += (size_t)3 * HIDc * DdPad * 2;
    ushort* WtHid = (ushort*)(ws + off); off += (size_t)6 * HIDc * HIDc * 2;
    ushort* WtB   = (ushort*)(ws + off); off += (size_t)3 * NbPad * HIDc * 2;
    float*  part  = (float*) (ws + off); off += (size_t)SPLITK * Mm * HIDc * 4;
    ushort* xb    = (ushort*)(ws + off); off += (size_t)Mm * DdPad * 2;

    build_x_kernel<<<Mm, 256, 0, stream>>>(hist, nid, adj, emb, xb, level);

    for (int i = 0; i < 3; i++)
        transpose_w<<<dim3(DdPad / 32, HIDc / 64), 256, 0, stream>>>(
            W_in + (size_t)i * Dd * HIDc, WtIn + (size_t)i * HIDc * DdPad,
            Dd, HIDc, DdPad);
    for (int l = 0; l < 6; l++)
        transpose_w<<<dim3(HIDc / 32, HIDc / 64), 256, 0, stream>>>(
            W_hid + (size_t)l * HIDc * HIDc, WtHid + (size_t)l * HIDc * HIDc,
            HIDc, HIDc, HIDc);
    for (int i = 0; i < 3; i++)
        transpose_w<<<dim3(HIDc / 32, NbPad / 64), 256, 0, stream>>>(
            W_b + (size_t)i * HIDc * Dd, WtB + (size_t)i * NbPad * HIDc,
            HIDc, Dd, HIDc);

    for (int i = 0; i < 3; i++) {
        const float* bi  = b_in  + (size_t)i * HIDc;
        const float* bh0 = b_hid + (size_t)(i * 2 + 0) * HIDc;
        const float* bh1 = b_hid + (size_t)(i * 2 + 1) * HIDc;
        const float* Wfi = W_f   + (size_t)i * HIDc * HORc;
        const float* bfi = b_f   + (size_t)i * HORc;
        const float* bbi = b_b   + (size_t)i * Dd;

        // partial[s] = x @ W_in (split-K over K=DdPad), reduce -> hA (bf16)
        gemm_mfma<128, 128, 0>
            <<<dim3(Mm / 128, HIDc / 128, SPLITK), 256, 0, stream>>>(
            xb, DdPad, WtIn + (size_t)i * HIDc * DdPad, DdPad,
            nullptr, nullptr, 0, part, HIDc, DdPad, HIDc, KCHUNK);
        reduce_hin<<<Mm * HIDc / 1024, 256, 0, stream>>>(part, bi, hA);

        // hidden layers (32x32 tiles -> 1024 blocks: 4 blocks/CU of TLP)
        gemm_mfma<32, 32, 1>
            <<<dim3(Mm / 32, HIDc / 32, 1), 256, 0, stream>>>(
            hA, HIDc, WtHid + (size_t)(2 * i) * HIDc * HIDc, HIDc,
            bh0, nullptr, 0, hB, HIDc, HIDc, HIDc, HIDc);
        gemm_mfma<32, 32, 1>
            <<<dim3(Mm / 32, HIDc / 32, 1), 256, 0, stream>>>(
            hB, HIDc, WtHid + (size_t)(2 * i + 1) * HIDc * HIDc, HIDc,
            bh1, nullptr, 0, hA, HIDc, HIDc, HIDc, HIDc);

        // forecast accumulate
        gemm_forecast_kernel<<<(Mm * HORc + 255) / 256, 256, 0, stream>>>(
            hA, Wfi, bfi, fc, i > 0 ? 1 : 0);

        // backcast
        if (i < 2) {
            // xb = relu(xb - (hA @ W_b + b_b)), in-place bf16
            gemm_mfma<128, 128, 3>
                <<<dim3(Mm / 128, NbPad / 128, 1), 256, 0, stream>>>(
                hA, HIDc, WtB + (size_t)i * NbPad * HIDc, HIDc,
                bbi, xb, DdPad, xb, DdPad, HIDc, Dd, HIDc);
        } else {
            // final: bout = relu(xb - (hA @ W_b + b_b)), fp32 output
            gemm_mfma<128, 128, 2>
                <<<dim3(Mm / 128, NbPad / 128, 1), 256, 0, stream>>>(
                hA, HIDc, WtB + (size_t)i * NbPad * HIDc, HIDc,
                bbi, xb, DdPad, bout, Dd, HIDc, Dd, HIDc);
        }
    }

    finalize_kernel<<<(Mm * HORc + 255) / 256, 256, 0, stream>>>(fc, level, fout);
}

// Round 5
// 856.178 us; speedup vs baseline: 1.1717x; 1.0414x over previous
//
#include <hip/hip_runtime.h>

// Problem constants
#define Bq   8
#define Nn   512
#define Tt   24
#define NIDc 64
#define HIDc 256
#define HORc 24
#define Dd   12376      // Tt + Nn*Tt + NIDc
#define Mm   4096       // Bq*Nn
#define DdPad 12384     // Dd padded to multiple of 32 (K dim of x / W_in^T)
#define NbPad 12416     // Dd padded to multiple of 128 (N-pad for W_b^T rows)
#define SPLITK 8
#define KCHUNK 1568     // 8*1568 >= 12384, mult of 32

typedef float  f32x4  __attribute__((ext_vector_type(4)));
typedef short  bf16x8 __attribute__((ext_vector_type(8)));

__device__ __forceinline__ ushort f2bf(float f) {
    unsigned u = __float_as_uint(f);
    u += 0x7FFF + ((u >> 16) & 1);          // RNE; inputs finite
    return (ushort)(u >> 16);
}
__device__ __forceinline__ float bf2f(ushort h) {
    return __uint_as_float(((unsigned)h) << 16);
}

// async 16B/lane global->LDS: LDS dest = wave-uniform base + lane*16
#define ASYNC16(g, l) __builtin_amdgcn_global_load_lds(                        \
    (const __attribute__((address_space(1))) unsigned*)(g),                    \
    (__attribute__((address_space(3))) unsigned*)(l), 16, 0, 0)

// ---------------------------------------------------------------------------
// build level + x0 (bf16, row stride DdPad, pad cols zeroed)
// ---------------------------------------------------------------------------
__global__ __launch_bounds__(256) void build_x_kernel(
    const float* __restrict__ hist, const int* __restrict__ nid,
    const float* __restrict__ adj, const float* __restrict__ emb,
    ushort* __restrict__ x, float* __restrict__ level)
{
    int bn = blockIdx.x;
    int b  = bn >> 9;
    __shared__ float sh[Tt];
    __shared__ float slv;
    int tid = threadIdx.x;
    const float* hrow = hist + (size_t)bn * Tt;
    if (tid < Tt) sh[tid] = hrow[tid];
    __syncthreads();
    if (tid == 0) {
        float m = sh[0];
        #pragma unroll
        for (int t = 1; t < Tt; t++) m = fmaxf(m, sh[t]);
        slv = m;
        level[bn] = m;
    }
    __syncthreads();
    float lv  = slv;
    float inv = (lv == 0.0f) ? 0.0f : 1.0f / lv;
    ushort* xr = x + (size_t)bn * DdPad;
    if (tid < Tt) xr[tid] = f2bf(sh[tid] * inv);
    const float* hb   = hist + (size_t)b * Nn * Tt;
    const float* arow = adj  + (size_t)bn * Nn;
    // vectorized: 8 consecutive elements per thread -> one 16B store
    for (int base = tid * 8; base < Nn * Tt; base += 256 * 8) {
        bf16x8 pack;
        #pragma unroll
        for (int e = 0; e < 8; e++) {
            int idx = base + e;
            int m_ = idx / Tt;
            int t  = idx - m_ * Tt;
            float v = arow[m_] * hb[m_ * Tt + t];
            float r = (v - lv) * inv;
            pack[e] = (short)f2bf((r > 0.0f) ? r : 0.0f);
        }
        *(bf16x8*)(xr + Tt + base) = pack;   // (Tt+base)*2 = 48+16k: aligned
    }
    if (tid < NIDc) {
        int id = nid[bn];
        xr[Tt + Nn * Tt + tid] = f2bf(emb[(size_t)id * NIDc + tid]);
    }
    if (tid < DdPad - Dd) xr[Dd + tid] = 0;   // zero K-pad cols
}

// ---------------------------------------------------------------------------
// Batched: W[z][K][N] fp32 -> Bt[z][n][k] bf16, K zero-padded to Kpad.
// blockIdx.z selects the matrix.
// ---------------------------------------------------------------------------
__global__ __launch_bounds__(256) void transpose_w(
    const float* __restrict__ W0, ushort* __restrict__ Bt0,
    int K, int N, int Kpad, size_t wstep, size_t btstep)
{
    const float*  W  = W0  + (size_t)blockIdx.z * wstep;
    ushort*       Bt = Bt0 + (size_t)blockIdx.z * btstep;
    __shared__ ushort tile[32][72];
    const int k0 = blockIdx.x * 32;
    const int n0 = blockIdx.y * 64;
    const int tid = threadIdx.x;
    #pragma unroll
    for (int i = 0; i < 8; i++) {
        const int idx = tid + i * 256;
        const int kk = idx >> 6;
        const int nn = idx & 63;
        const int gk = k0 + kk, gn = n0 + nn;
        const float v = (gk < K && gn < N) ? W[(size_t)gk * N + gn] : 0.0f;
        tile[kk][nn] = f2bf(v);
    }
    __syncthreads();
    const int n  = tid >> 2;
    const int kc = (tid & 3) << 3;
    uint4 o;
    o.x = (unsigned)tile[kc + 0][n] | ((unsigned)tile[kc + 1][n] << 16);
    o.y = (unsigned)tile[kc + 2][n] | ((unsigned)tile[kc + 3][n] << 16);
    o.z = (unsigned)tile[kc + 4][n] | ((unsigned)tile[kc + 5][n] << 16);
    o.w = (unsigned)tile[kc + 6][n] | ((unsigned)tile[kc + 7][n] << 16);
    *(uint4*)(Bt + (size_t)(n0 + n) * Kpad + k0 + kc) = o;
}

// ---------------------------------------------------------------------------
// bf16 MFMA GEMM, 128x128 tile, 4 waves (2x2), mfma_f32_16x16x32_bf16.
// Double-buffered LDS, raw s_barrier + counted vmcnt (T3/T4).
// OPERANDS SWAPPED: lane owns 4 consecutive cols.
// EPI 0: fp32 split-K partial; EPI 2: fp32 C = relu(X-(acc+b));
// EPI 3: bf16 C = relu(X-(acc+b)) in-place.
// ---------------------------------------------------------------------------
template <int TM, int TN, int EPI>
__global__ __launch_bounds__(256) void gemm_mfma(
    const ushort* __restrict__ A, int lda,
    const ushort* __restrict__ Bt, int ldbt,
    const float* __restrict__ bias,
    const ushort* __restrict__ X, int ldx,
    void* __restrict__ Cp, int ldc,
    int K, int N, int chunk)
{
    constexpr int WI = TM / 32;
    constexpr int WJ = TN / 32;
    constexpr int SA = TM / 16;          // 16-row async segments of A
    constexpr int SB = TN / 16;
    constexpr int LPW = (SA + SB) / 4;   // async loads per wave per stage
    static_assert((SA + SB) % 4 == 0, "uniform loads per wave required");
    static_assert(LPW == 1 || LPW == 2 || LPW == 4, "vmcnt literal");
    __shared__ ushort As[2][TM * 32];
    __shared__ ushort Bs[2][TN * 32];

    const int tid  = threadIdx.x;
    const int row0 = blockIdx.x * TM;
    const int col0 = blockIdx.y * TN;
    const int spl  = blockIdx.z;
    const int kstart = spl * chunk;
    const int kend   = min(K, kstart + chunk);
    const int iters  = (kend - kstart) >> 5;   // K, chunk multiples of 32

    const int lane = tid & 63;
    const int wave = tid >> 6;
    const int quad = lane >> 4;
    const int l15  = lane & 15;
    const int wm   = (wave >> 1) * (TM / 2);
    const int wn   = (wave & 1) * (TN / 2);

    f32x4 acc[WI][WJ];
    #pragma unroll
    for (int i = 0; i < WI; i++)
        #pragma unroll
        for (int j = 0; j < WJ; j++)
            acc[i][j] = (f32x4){0.f, 0.f, 0.f, 0.f};

    auto stage = [&](int buf, int kb) {
        #pragma unroll
        for (int t = 0; t < LPW; t++) {
            const int s = wave + 4 * t;
            if (s < SA) {
                const int r = s * 16 + (lane >> 2);
                ASYNC16(A + (size_t)(row0 + r) * lda + kb + ((lane & 3) << 3),
                        &As[buf][s * 512]);
            } else {
                const int s2 = s - SA;
                const int r = s2 * 16 + (lane >> 2);
                ASYNC16(Bt + (size_t)(col0 + r) * ldbt + kb + ((lane & 3) << 3),
                        &Bs[buf][s2 * 512]);
            }
        }
    };

    stage(0, kstart);

    // epilogue operand prefetch (latency hides under the whole K-loop)
    float4  bpre[WJ];
    ushort4 xpre[WI][WJ];
    bool    cok[WJ];
    #pragma unroll
    for (int j = 0; j < WJ; j++) {
        const int c0 = col0 + wn + j * 16 + quad * 4;
        cok[j] = (c0 < N);     // N%4==0 -> whole 4-vector valid iff c0<N
        if constexpr (EPI >= 2) {
            bpre[j] = cok[j] ? *(const float4*)&bias[c0]
                             : float4{0.f, 0.f, 0.f, 0.f};
        }
    }
    if constexpr (EPI >= 2) {
        #pragma unroll
        for (int i = 0; i < WI; i++) {
            const int row = row0 + wm + i * 16 + l15;
            #pragma unroll
            for (int j = 0; j < WJ; j++) {
                const int c0 = col0 + wn + j * 16 + quad * 4;
                xpre[i][j] = cok[j]
                    ? *(const ushort4*)&X[(size_t)row * ldx + c0]
                    : ushort4{0, 0, 0, 0};
            }
        }
    }

    for (int kt = 0; kt < iters; ++kt) {
        const int cur = kt & 1;
        if (kt + 1 < iters) {
            stage(cur ^ 1, kstart + ((kt + 1) << 5));
            // wait for everything except the LPW loads just issued
            if constexpr (LPW == 4)
                asm volatile("s_waitcnt vmcnt(4)" ::: "memory");
            else if constexpr (LPW == 2)
                asm volatile("s_waitcnt vmcnt(2)" ::: "memory");
            else
                asm volatile("s_waitcnt vmcnt(1)" ::: "memory");
        } else {
            asm volatile("s_waitcnt vmcnt(0)" ::: "memory");
        }
        __builtin_amdgcn_s_barrier();          // cur fully staged, all waves
        __builtin_amdgcn_sched_barrier(0);     // pin: no hoist above barrier

        bf16x8 af[WI], bfr[WJ];
        #pragma unroll
        for (int i = 0; i < WI; i++)
            af[i] = *(const bf16x8*)&As[cur][(wm + i * 16 + l15) * 32 + quad * 8];
        #pragma unroll
        for (int j = 0; j < WJ; j++)
            bfr[j] = *(const bf16x8*)&Bs[cur][(wn + j * 16 + l15) * 32 + quad * 8];
        #pragma unroll
        for (int i = 0; i < WI; i++)
            #pragma unroll
            for (int j = 0; j < WJ; j++)
                acc[i][j] = __builtin_amdgcn_mfma_f32_16x16x32_bf16(
                    bfr[j], af[i], acc[i][j], 0, 0, 0);   // SWAPPED operands

        __builtin_amdgcn_sched_barrier(0);     // pin: no sink below barrier
        __builtin_amdgcn_s_barrier();          // cur free for restaging
    }

    // Vector epilogue: lane owns 4 consecutive cols at one row.
    #pragma unroll
    for (int i = 0; i < WI; i++) {
        const int row = row0 + wm + i * 16 + l15;
        #pragma unroll
        for (int j = 0; j < WJ; j++) {
            const int c0 = col0 + wn + j * 16 + quad * 4;
            const f32x4 v = acc[i][j];
            if constexpr (EPI == 0) {
                *(f32x4*)&((float*)Cp)[(size_t)spl * Mm * HIDc +
                                       (size_t)row * ldc + c0] = v;
            } else if constexpr (EPI == 2) {
                if (cok[j]) {
                    f32x4 o;
                    o[0] = fmaxf(bf2f(xpre[i][j].x) - (v[0] + bpre[j].x), 0.f);
                    o[1] = fmaxf(bf2f(xpre[i][j].y) - (v[1] + bpre[j].y), 0.f);
                    o[2] = fmaxf(bf2f(xpre[i][j].z) - (v[2] + bpre[j].z), 0.f);
                    o[3] = fmaxf(bf2f(xpre[i][j].w) - (v[3] + bpre[j].w), 0.f);
                    *(f32x4*)&((float*)Cp)[(size_t)row * ldc + c0] = o;
                }
            } else {
                if (cok[j]) {
                    ushort4 o;
                    o.x = f2bf(fmaxf(bf2f(xpre[i][j].x) - (v[0] + bpre[j].x), 0.f));
                    o.y = f2bf(fmaxf(bf2f(xpre[i][j].y) - (v[1] + bpre[j].y), 0.f));
                    o.z = f2bf(fmaxf(bf2f(xpre[i][j].z) - (v[2] + bpre[j].z), 0.f));
                    o.w = f2bf(fmaxf(bf2f(xpre[i][j].w) - (v[3] + bpre[j].w), 0.f));
                    *(ushort4*)&((ushort*)Cp)[(size_t)row * ldc + c0] = o;
                }
            }
        }
    }
}

// ---------------------------------------------------------------------------
// Hidden-layer GEMM: C = relu(A @ Bt^T + bias) bf16, M=Mm, N=K=256.
// 64x64 tile. K=256 fits LDS entirely: single burst stage (A 32KB + B 32KB),
// ONE vmcnt(0)+barrier, then 32 MFMAs with no further barriers.
// LDS: 32 segments x 512 ushorts each (FIXED: was /16 -> 16x overrun).
// ---------------------------------------------------------------------------
__global__ __launch_bounds__(256) void gemm_hidden(
    const ushort* __restrict__ A,      // [Mm][256] bf16
    const ushort* __restrict__ Bt,     // [256][256] bf16 (pre-transposed)
    const float* __restrict__ bias,
    ushort* __restrict__ C)            // [Mm][256] bf16
{
    // seg = kt*4 + (r>>4); ushort idx = seg*512 + (r&15)*32 + q*8
    __shared__ ushort As[32 * 512];    // 64 rows x 256 k = 32 KB
    __shared__ ushort Bs[32 * 512];

    const int tid  = threadIdx.x;
    const int row0 = blockIdx.x * 64;
    const int col0 = blockIdx.y * 64;
    const int lane = tid & 63;
    const int wave = tid >> 6;
    const int quad = lane >> 4;
    const int l15  = lane & 15;
    const int wm   = (wave >> 1) * 32;
    const int wn   = (wave & 1) * 32;

    // 64 segments total (32 A + 32 B), 16 per wave
    #pragma unroll
    for (int t = 0; t < 8; t++) {
        const int s = wave + 4 * t;            // A segs 0..31
        const int kt = s >> 2;
        const int r  = ((s & 3) << 4) + (lane >> 2);
        ASYNC16(A + (size_t)(row0 + r) * HIDc + (kt << 5) + ((lane & 3) << 3),
                &As[s * 512]);
    }
    #pragma unroll
    for (int t = 0; t < 8; t++) {
        const int s = wave + 4 * t;            // B segs 0..31
        const int kt = s >> 2;
        const int r  = ((s & 3) << 4) + (lane >> 2);
        ASYNC16(Bt + (size_t)(col0 + r) * HIDc + (kt << 5) + ((lane & 3) << 3),
                &Bs[s * 512]);
    }

    // bias prefetch under the staging latency
    float4 bpre[2];
    #pragma unroll
    for (int j = 0; j < 2; j++)
        bpre[j] = *(const float4*)&bias[col0 + wn + j * 16 + quad * 4];

    f32x4 acc[2][2];
    #pragma unroll
    for (int i = 0; i < 2; i++)
        #pragma unroll
        for (int j = 0; j < 2; j++)
            acc[i][j] = (f32x4){0.f, 0.f, 0.f, 0.f};

    asm volatile("s_waitcnt vmcnt(0)" ::: "memory");
    __builtin_amdgcn_s_barrier();
    __builtin_amdgcn_sched_barrier(0);

    #pragma unroll
    for (int kt = 0; kt < 8; kt++) {
        bf16x8 af[2], bfr[2];
        #pragma unroll
        for (int i = 0; i < 2; i++) {
            const int r = wm + i * 16 + l15;
            af[i] = *(const bf16x8*)&As[(kt * 4 + (r >> 4)) * 512 +
                                        (r & 15) * 32 + quad * 8];
        }
        #pragma unroll
        for (int j = 0; j < 2; j++) {
            const int r = wn + j * 16 + l15;
            bfr[j] = *(const bf16x8*)&Bs[(kt * 4 + (r >> 4)) * 512 +
                                         (r & 15) * 32 + quad * 8];
        }
        #pragma unroll
        for (int i = 0; i < 2; i++)
            #pragma unroll
            for (int j = 0; j < 2; j++)
                acc[i][j] = __builtin_amdgcn_mfma_f32_16x16x32_bf16(
                    bfr[j], af[i], acc[i][j], 0, 0, 0);   // swapped operands
    }

    #pragma unroll
    for (int i = 0; i < 2; i++) {
        const int row = row0 + wm + i * 16 + l15;
        #pragma unroll
        for (int j = 0; j < 2; j++) {
            const int c0 = col0 + wn + j * 16 + quad * 4;
            const f32x4 v = acc[i][j];
            ushort4 o;
            o.x = f2bf(fmaxf(v[0] + bpre[j].x, 0.f));
            o.y = f2bf(fmaxf(v[1] + bpre[j].y, 0.f));
            o.z = f2bf(fmaxf(v[2] + bpre[j].z, 0.f));
            o.w = f2bf(fmaxf(v[3] + bpre[j].w, 0.f));
            *(ushort4*)&C[(size_t)row * HIDc + c0] = o;
        }
    }
}

// ---------------------------------------------------------------------------
// h = relu(sum_s partial[s] + bias) -> bf16   (float4 per thread)
// ---------------------------------------------------------------------------
__global__ __launch_bounds__(256) void reduce_hin(
    const float* __restrict__ partial, const float* __restrict__ bias,
    ushort* __restrict__ h)
{
    const int gid = (blockIdx.x * 256 + threadIdx.x) * 4;
    f32x4 s = *(const f32x4*)&bias[gid & (HIDc - 1)];
    #pragma unroll
    for (int j = 0; j < SPLITK; j++)
        s += *(const f32x4*)&partial[(size_t)j * (Mm * HIDc) + gid];
    ushort4 o;
    o.x = f2bf(fmaxf(s[0], 0.f));
    o.y = f2bf(fmaxf(s[1], 0.f));
    o.z = f2bf(fmaxf(s[2], 0.f));
    o.w = f2bf(fmaxf(s[3], 0.f));
    *(ushort4*)&h[gid] = o;
}

// ---------------------------------------------------------------------------
// fc[4096x24] (+)= h @ Wf + bf; if level != nullptr also emit
// out = fc_total * level (fused finalize for the last block).
// ---------------------------------------------------------------------------
__global__ __launch_bounds__(256) void gemm_forecast_kernel(
    const ushort* __restrict__ h, const float* __restrict__ Wf,
    const float* __restrict__ bf, float* __restrict__ fc,
    const float* __restrict__ level, float* __restrict__ out, int accumulate)
{
    int gid = blockIdx.x * 256 + threadIdx.x;
    if (gid >= Mm * HORc) return;
    int row = gid / HORc;
    int col = gid - row * HORc;
    const ushort* hr = h + (size_t)row * HIDc;
    float acc = 0.0f;
    #pragma unroll 4
    for (int k = 0; k < HIDc; k++)
        acc = fmaf(bf2f(hr[k]), Wf[k * HORc + col], acc);
    acc += bf[col];
    if (accumulate) acc += fc[gid];
    if (level) out[gid] = acc * level[row];   // last block: fused finalize
    else       fc[gid]  = acc;
}

// ---------------------------------------------------------------------------
extern "C" void kernel_launch(void* const* d_in, const int* in_sizes, int n_in,
                              void* d_out, int out_size, void* d_ws, size_t ws_size,
                              hipStream_t stream)
{
    const float* hist  = (const float*)d_in[0];
    const int*   nid   = (const int*)  d_in[1];
    const float* adj   = (const float*)d_in[3];
    const float* emb   = (const float*)d_in[4];
    const float* W_in  = (const float*)d_in[5];
    const float* b_in  = (const float*)d_in[6];
    const float* W_hid = (const float*)d_in[7];
    const float* b_hid = (const float*)d_in[8];
    const float* W_f   = (const float*)d_in[9];
    const float* b_f   = (const float*)d_in[10];
    const float* W_b   = (const float*)d_in[11];
    const float* b_b   = (const float*)d_in[12];

    float* bout = (float*)d_out;                       // backcast (B,N,D) fp32
    float* fout = (float*)d_out + (size_t)Mm * Dd;     // forecast region

    // ws layout (~178 MB)
    char* ws = (char*)d_ws;
    size_t off = 0;
    float*  level = (float*) (ws + off); off += 16384;
    float*  fc    = (float*) (ws + off); off += (size_t)Mm * HORc * 4;
    ushort* hA    = (ushort*)(ws + off); off += (size_t)Mm * HIDc * 2;
    ushort* hB    = (ushort*)(ws + off); off += (size_t)Mm * HIDc * 2;
    ushort* WtIn  = (ushort*)(ws + off); off += (size_t)3 * HIDc * DdPad * 2;
    ushort* WtHid = (ushort*)(ws + off); off += (size_t)6 * HIDc * HIDc * 2;
    ushort* WtB   = (ushort*)(ws + off); off += (size_t)3 * NbPad * HIDc * 2;
    float*  part  = (float*) (ws + off); off += (size_t)SPLITK * Mm * HIDc * 4;
    ushort* xb    = (ushort*)(ws + off); off += (size_t)Mm * DdPad * 2;

    build_x_kernel<<<Mm, 256, 0, stream>>>(hist, nid, adj, emb, xb, level);

    // batched weight transposes: 3 launches
    transpose_w<<<dim3(DdPad / 32, HIDc / 64, 3), 256, 0, stream>>>(
        W_in, WtIn, Dd, HIDc, DdPad,
        (size_t)Dd * HIDc, (size_t)HIDc * DdPad);
    transpose_w<<<dim3(HIDc / 32, HIDc / 64, 6), 256, 0, stream>>>(
        W_hid, WtHid, HIDc, HIDc, HIDc,
        (size_t)HIDc * HIDc, (size_t)HIDc * HIDc);
    transpose_w<<<dim3(HIDc / 32, NbPad / 64, 3), 256, 0, stream>>>(
        W_b, WtB, HIDc, Dd, HIDc,
        (size_t)HIDc * Dd, (size_t)NbPad * HIDc);

    for (int i = 0; i < 3; i++) {
        const float* bi  = b_in  + (size_t)i * HIDc;
        const float* bh0 = b_hid + (size_t)(i * 2 + 0) * HIDc;
        const float* bh1 = b_hid + (size_t)(i * 2 + 1) * HIDc;
        const float* Wfi = W_f   + (size_t)i * HIDc * HORc;
        const float* bfi = b_f   + (size_t)i * HORc;
        const float* bbi = b_b   + (size_t)i * Dd;

        // partial[s] = x @ W_in (split-K over K=DdPad), reduce -> hA (bf16)
        gemm_mfma<128, 128, 0>
            <<<dim3(Mm / 128, HIDc / 128, SPLITK), 256, 0, stream>>>(
            xb, DdPad, WtIn + (size_t)i * HIDc * DdPad, DdPad,
            nullptr, nullptr, 0, part, HIDc, DdPad, HIDc, KCHUNK);
        reduce_hin<<<Mm * HIDc / 1024, 256, 0, stream>>>(part, bi, hA);

        // hidden layers: single-stage 64x64 kernel, one barrier total
        gemm_hidden<<<dim3(Mm / 64, HIDc / 64), 256, 0, stream>>>(
            hA, WtHid + (size_t)(2 * i) * HIDc * HIDc, bh0, hB);
        gemm_hidden<<<dim3(Mm / 64, HIDc / 64), 256, 0, stream>>>(
            hB, WtHid + (size_t)(2 * i + 1) * HIDc * HIDc, bh1, hA);

        // forecast accumulate (+ fused finalize on last block)
        gemm_forecast_kernel<<<(Mm * HORc + 255) / 256, 256, 0, stream>>>(
            hA, Wfi, bfi, fc, (i == 2) ? level : nullptr, fout, i > 0 ? 1 : 0);

        // backcast
        if (i < 2) {
            // xb = relu(xb - (hA @ W_b + b_b)), in-place bf16
            gemm_mfma<128, 128, 3>
                <<<dim3(Mm / 128, NbPad / 128, 1), 256, 0, stream>>>(
                hA, HIDc, WtB + (size_t)i * NbPad * HIDc, HIDc,
                bbi, xb, DdPad, xb, DdPad, HIDc, Dd, HIDc);
        } else {
            // final: bout = relu(xb - (hA @ W_b + b_b)), fp32 output
            gemm_mfma<128, 128, 2>
                <<<dim3(Mm / 128, NbPad / 128, 1), 256, 0, stream>>>(
                hA, HIDc, WtB + (size_t)i * NbPad * HIDc, HIDc,
                bbi, xb, DdPad, bout, Dd, HIDc, Dd, HIDc);
        }
    }
}